// Round 1
// baseline (1280.966 us; speedup 1.0000x reference)
//
#include <hip/hip_runtime.h>
#include <math.h>

#define E_TOT   640000
#define NN      20000
#define DIM     128
#define EDGE_DIM 16
#define K1      272   // 2*DIM + EDGE_DIM
#define KN      256   // DIM + DIM

__device__ __forceinline__ float silu_f(float x)    { return x / (1.0f + __expf(-x)); }
__device__ __forceinline__ float sigmoid_f(float x) { return 1.0f / (1.0f + __expf(-x)); }

// ---------------------------------------------------------------------------
// Edge kernel: per 64-edge tile, fused  X@Wm1 -> silu -> @Wm2 -> silu -> att
// -> mask -> atomic scatter-add into agg[row].
// Thread layout: 256 threads; ty = tid>>5 (8 row groups of 8 edges),
// tx = tid&31; each thread owns cols d = tx + 32*c (c=0..3) for 8 edges.
// ---------------------------------------------------------------------------
__global__ __launch_bounds__(256) void edge_kernel(
    const float* __restrict__ h, const int* __restrict__ ei,
    const float* __restrict__ ea, const float* __restrict__ emask,
    const float* __restrict__ Wm1, const float* __restrict__ bm1,
    const float* __restrict__ Wm2, const float* __restrict__ bm2,
    const float* __restrict__ Wa,  const float* __restrict__ ba,
    float* __restrict__ agg)
{
    __shared__ int   s_row[64];
    __shared__ int   s_col[64];
    __shared__ float s_mask[64];
    __shared__ float s_X[64][17];    // K-slice of gathered input
    __shared__ float s_W[16][128];   // K-slice of weights
    __shared__ float s_H[64][130];   // hidden activations

    const int tid = threadIdx.x;
    const int e0  = blockIdx.x * 64;

    if (tid < 64) {
        s_row[tid]  = ei[e0 + tid];
        s_col[tid]  = ei[E_TOT + e0 + tid];
        s_mask[tid] = emask[e0 + tid];
    }
    __syncthreads();

    const int ty = tid >> 5;
    const int tx = tid & 31;

    float acc[8][4];
    #pragma unroll
    for (int i = 0; i < 8; ++i)
        #pragma unroll
        for (int c = 0; c < 4; ++c) acc[i][c] = 0.f;

    const int le = tid >> 2;         // 0..63: edge for X staging
    const int lj = (tid & 3) * 4;    // 0,4,8,12

    // ---------------- layer 1: X[64,272] @ Wm1[272,128] ----------------
    for (int kt = 0; kt < K1 / 16; ++kt) {
        const int k0 = kt * 16;
        {   // stage X slice
            int k = k0 + lj;
            const float* src;
            if (k < DIM)            src = h  + (size_t)s_row[le] * DIM + k;
            else if (k < 2 * DIM)   src = h  + (size_t)s_col[le] * DIM + (k - DIM);
            else                    src = ea + (size_t)(e0 + le) * EDGE_DIM + (k - 2 * DIM);
            float4 v = *reinterpret_cast<const float4*>(src);
            s_X[le][lj + 0] = v.x; s_X[le][lj + 1] = v.y;
            s_X[le][lj + 2] = v.z; s_X[le][lj + 3] = v.w;
        }
        {   // stage W slice
            int kk = tid >> 4;
            int d0 = (tid & 15) * 8;
            const float4* src = reinterpret_cast<const float4*>(Wm1 + (size_t)(k0 + kk) * DIM + d0);
            float4 a = src[0], b = src[1];
            float* dst = &s_W[kk][d0];
            dst[0] = a.x; dst[1] = a.y; dst[2] = a.z; dst[3] = a.w;
            dst[4] = b.x; dst[5] = b.y; dst[6] = b.z; dst[7] = b.w;
        }
        __syncthreads();
        #pragma unroll
        for (int kk = 0; kk < 16; ++kk) {
            float xv[8];
            #pragma unroll
            for (int i = 0; i < 8; ++i) xv[i] = s_X[ty * 8 + i][kk];
            #pragma unroll
            for (int c = 0; c < 4; ++c) {
                float wv = s_W[kk][tx + 32 * c];
                #pragma unroll
                for (int i = 0; i < 8; ++i) acc[i][c] = fmaf(xv[i], wv, acc[i][c]);
            }
        }
        __syncthreads();
    }

    // bias + silu -> s_H
    {
        float b[4];
        #pragma unroll
        for (int c = 0; c < 4; ++c) b[c] = bm1[tx + 32 * c];
        #pragma unroll
        for (int i = 0; i < 8; ++i)
            #pragma unroll
            for (int c = 0; c < 4; ++c)
                s_H[ty * 8 + i][tx + 32 * c] = silu_f(acc[i][c] + b[c]);
    }
    __syncthreads();

    // ---------------- layer 2: H[64,128] @ Wm2[128,128] ----------------
    #pragma unroll
    for (int i = 0; i < 8; ++i)
        #pragma unroll
        for (int c = 0; c < 4; ++c) acc[i][c] = 0.f;

    for (int kt = 0; kt < DIM / 16; ++kt) {
        const int k0 = kt * 16;
        {
            int kk = tid >> 4;
            int d0 = (tid & 15) * 8;
            const float4* src = reinterpret_cast<const float4*>(Wm2 + (size_t)(k0 + kk) * DIM + d0);
            float4 a = src[0], b = src[1];
            float* dst = &s_W[kk][d0];
            dst[0] = a.x; dst[1] = a.y; dst[2] = a.z; dst[3] = a.w;
            dst[4] = b.x; dst[5] = b.y; dst[6] = b.z; dst[7] = b.w;
        }
        __syncthreads();
        #pragma unroll
        for (int kk = 0; kk < 16; ++kk) {
            float xv[8];
            #pragma unroll
            for (int i = 0; i < 8; ++i) xv[i] = s_H[ty * 8 + i][k0 + kk];
            #pragma unroll
            for (int c = 0; c < 4; ++c) {
                float wv = s_W[kk][tx + 32 * c];
                #pragma unroll
                for (int i = 0; i < 8; ++i) acc[i][c] = fmaf(xv[i], wv, acc[i][c]);
            }
        }
        __syncthreads();
    }

    // bias + silu, attention dot, mask, scatter
    {
        float b[4], wa[4];
        #pragma unroll
        for (int c = 0; c < 4; ++c) { b[c] = bm2[tx + 32 * c]; wa[c] = Wa[tx + 32 * c]; }
        const float ba0 = ba[0];
        #pragma unroll
        for (int i = 0; i < 8; ++i) {
            float p = 0.f;
            #pragma unroll
            for (int c = 0; c < 4; ++c) {
                float v = silu_f(acc[i][c] + b[c]);
                acc[i][c] = v;
                p = fmaf(v, wa[c], p);
            }
            // reduce across the 32 lanes sharing this ty (xor masks < 32
            // stay within each 32-lane half of the wave)
            #pragma unroll
            for (int m = 16; m >= 1; m >>= 1) p += __shfl_xor(p, m, 64);
            const int e = ty * 8 + i;
            const float scale = sigmoid_f(p + ba0) * s_mask[e];
            float* dst = agg + (size_t)s_row[e] * DIM;
            #pragma unroll
            for (int c = 0; c < 4; ++c)
                atomicAdd(dst + tx + 32 * c, acc[i][c] * scale);
        }
    }
}

// ---------------------------------------------------------------------------
// Node kernel: [h|agg][64,256] @ Wn1 -> silu -> @Wn2 -> +bn2, residual, flags
// ---------------------------------------------------------------------------
__global__ __launch_bounds__(256) void node_kernel(
    const float* __restrict__ h, const float* __restrict__ agg,
    const float* __restrict__ flags,
    const float* __restrict__ Wn1, const float* __restrict__ bn1,
    const float* __restrict__ Wn2, const float* __restrict__ bn2,
    float* __restrict__ out)
{
    __shared__ float s_X[64][17];
    __shared__ float s_W[16][128];
    __shared__ float s_H[64][130];

    const int tid = threadIdx.x;
    const int n0  = blockIdx.x * 64;
    const int ty = tid >> 5;
    const int tx = tid & 31;

    float acc[8][4];
    #pragma unroll
    for (int i = 0; i < 8; ++i)
        #pragma unroll
        for (int c = 0; c < 4; ++c) acc[i][c] = 0.f;

    const int ln = tid >> 2;
    const int lj = (tid & 3) * 4;

    for (int kt = 0; kt < KN / 16; ++kt) {
        const int k0 = kt * 16;
        {
            int k = k0 + lj;
            int n = n0 + ln;
            float4 v = make_float4(0.f, 0.f, 0.f, 0.f);
            if (n < NN) {
                const float* src = (k < DIM) ? (h   + (size_t)n * DIM + k)
                                             : (agg + (size_t)n * DIM + (k - DIM));
                v = *reinterpret_cast<const float4*>(src);
            }
            s_X[ln][lj + 0] = v.x; s_X[ln][lj + 1] = v.y;
            s_X[ln][lj + 2] = v.z; s_X[ln][lj + 3] = v.w;
        }
        {
            int kk = tid >> 4;
            int d0 = (tid & 15) * 8;
            const float4* src = reinterpret_cast<const float4*>(Wn1 + (size_t)(k0 + kk) * DIM + d0);
            float4 a = src[0], b = src[1];
            float* dst = &s_W[kk][d0];
            dst[0] = a.x; dst[1] = a.y; dst[2] = a.z; dst[3] = a.w;
            dst[4] = b.x; dst[5] = b.y; dst[6] = b.z; dst[7] = b.w;
        }
        __syncthreads();
        #pragma unroll
        for (int kk = 0; kk < 16; ++kk) {
            float xv[8];
            #pragma unroll
            for (int i = 0; i < 8; ++i) xv[i] = s_X[ty * 8 + i][kk];
            #pragma unroll
            for (int c = 0; c < 4; ++c) {
                float wv = s_W[kk][tx + 32 * c];
                #pragma unroll
                for (int i = 0; i < 8; ++i) acc[i][c] = fmaf(xv[i], wv, acc[i][c]);
            }
        }
        __syncthreads();
    }

    {
        float b[4];
        #pragma unroll
        for (int c = 0; c < 4; ++c) b[c] = bn1[tx + 32 * c];
        #pragma unroll
        for (int i = 0; i < 8; ++i)
            #pragma unroll
            for (int c = 0; c < 4; ++c)
                s_H[ty * 8 + i][tx + 32 * c] = silu_f(acc[i][c] + b[c]);
    }
    __syncthreads();

    #pragma unroll
    for (int i = 0; i < 8; ++i)
        #pragma unroll
        for (int c = 0; c < 4; ++c) acc[i][c] = 0.f;

    for (int kt = 0; kt < DIM / 16; ++kt) {
        const int k0 = kt * 16;
        {
            int kk = tid >> 4;
            int d0 = (tid & 15) * 8;
            const float4* src = reinterpret_cast<const float4*>(Wn2 + (size_t)(k0 + kk) * DIM + d0);
            float4 a = src[0], b = src[1];
            float* dst = &s_W[kk][d0];
            dst[0] = a.x; dst[1] = a.y; dst[2] = a.z; dst[3] = a.w;
            dst[4] = b.x; dst[5] = b.y; dst[6] = b.z; dst[7] = b.w;
        }
        __syncthreads();
        #pragma unroll
        for (int kk = 0; kk < 16; ++kk) {
            float xv[8];
            #pragma unroll
            for (int i = 0; i < 8; ++i) xv[i] = s_H[ty * 8 + i][k0 + kk];
            #pragma unroll
            for (int c = 0; c < 4; ++c) {
                float wv = s_W[kk][tx + 32 * c];
                #pragma unroll
                for (int i = 0; i < 8; ++i) acc[i][c] = fmaf(xv[i], wv, acc[i][c]);
            }
        }
        __syncthreads();
    }

    {
        float b[4];
        #pragma unroll
        for (int c = 0; c < 4; ++c) b[c] = bn2[tx + 32 * c];
        #pragma unroll
        for (int i = 0; i < 8; ++i) {
            int n = n0 + ty * 8 + i;
            if (n < NN) {
                float fl = flags[n];
                #pragma unroll
                for (int c = 0; c < 4; ++c) {
                    int d = tx + 32 * c;
                    out[(size_t)n * DIM + d] = (h[(size_t)n * DIM + d] + acc[i][c] + b[c]) * fl;
                }
            }
        }
    }
}

extern "C" void kernel_launch(void* const* d_in, const int* in_sizes, int n_in,
                              void* d_out, int out_size, void* d_ws, size_t ws_size,
                              hipStream_t stream) {
    const float* h     = (const float*)d_in[0];
    const int*   ei    = (const int*)  d_in[1];
    const float* ea    = (const float*)d_in[2];
    const float* flags = (const float*)d_in[3];
    const float* emask = (const float*)d_in[4];
    const float* Wm1   = (const float*)d_in[5];
    const float* bm1   = (const float*)d_in[6];
    const float* Wm2   = (const float*)d_in[7];
    const float* bm2   = (const float*)d_in[8];
    const float* Wa    = (const float*)d_in[9];
    const float* ba    = (const float*)d_in[10];
    const float* Wn1   = (const float*)d_in[11];
    const float* bn1   = (const float*)d_in[12];
    const float* Wn2   = (const float*)d_in[13];
    const float* bn2   = (const float*)d_in[14];
    float* out = (float*)d_out;
    float* agg = (float*)d_ws;   // [NN, DIM] f32 accumulator

    hipMemsetAsync(agg, 0, (size_t)NN * DIM * sizeof(float), stream);
    edge_kernel<<<E_TOT / 64, 256, 0, stream>>>(h, ei, ea, emask,
                                                Wm1, bm1, Wm2, bm2, Wa, ba, agg);
    node_kernel<<<(NN + 63) / 64, 256, 0, stream>>>(h, agg, flags,
                                                    Wn1, bn1, Wn2, bn2, out);
}

// Round 2
// 437.054 us; speedup vs baseline: 2.9309x; 2.9309x over previous
//
#include <hip/hip_runtime.h>
#include <math.h>

#define E_TOT   640000
#define NN      20000
#define DIM     128
#define EDGE_DIM 16

typedef float f32x4 __attribute__((ext_vector_type(4)));
typedef short s16x8 __attribute__((ext_vector_type(8)));
typedef __bf16 bfx8 __attribute__((ext_vector_type(8)));

__device__ __forceinline__ unsigned short f2bf(float f) {
    unsigned u = __builtin_bit_cast(unsigned, f);
    u += 0x7fffu + ((u >> 16) & 1u);
    return (unsigned short)(u >> 16);
}
__device__ __forceinline__ float silu_f(float x)    { return x / (1.0f + __expf(-x)); }
__device__ __forceinline__ float sigmoid_f(float x) { return 1.0f / (1.0f + __expf(-x)); }

#define MFMA16(a, b, c) __builtin_amdgcn_mfma_f32_16x16x32_bf16( \
    __builtin_bit_cast(bfx8, (a)), __builtin_bit_cast(bfx8, (b)), (c), 0, 0, 0)

// ---------------------------------------------------------------------------
// prep: h (f32) -> h_bf (bf16)
// ---------------------------------------------------------------------------
__global__ void prep_h_kernel(const float* __restrict__ h,
                              unsigned short* __restrict__ h_bf, int n4) {
    int i = blockIdx.x * blockDim.x + threadIdx.x;
    if (i < n4) {
        float4 v = reinterpret_cast<const float4*>(h)[i];
        unsigned short* d = h_bf + i * 4;
        d[0] = f2bf(v.x); d[1] = f2bf(v.y); d[2] = f2bf(v.z); d[3] = f2bf(v.w);
    }
}

// ---------------------------------------------------------------------------
// prep: pack W[K][128] (f32) into fragment-major bf16 layout, K padded to Kp.
// Wp[(sg*128 + n)*8 + t] = (k < K) ? bf16(W[k*128+n]) : 0,  k = sg*8 + t.
// Lane l of an MFMA B-frag (k-step s, col n) then reads 8 contiguous bf16 at
// ((s*4 + (l>>4))*128 + n)*8.
// ---------------------------------------------------------------------------
__global__ void prep_w_kernel(const float* __restrict__ W,
                              unsigned short* __restrict__ Wp,
                              int K, int tot) {   // tot = Kp*128
    int id = blockIdx.x * blockDim.x + threadIdx.x;
    if (id >= tot) return;
    int t = id & 7;
    int n = (id >> 3) & 127;
    int sg = id >> 10;
    int k = sg * 8 + t;
    Wp[id] = (k < K) ? f2bf(W[(size_t)k * DIM + n]) : (unsigned short)0;
}

// ---------------------------------------------------------------------------
// Edge kernel: 64 edges/block, 4 waves, wave w owns output cols [32w,32w+32).
// bf16 MFMA 16x16x32 for both MLP layers; weights in registers.
// ---------------------------------------------------------------------------
__global__ __launch_bounds__(256, 2) void edge_kernel(
    const unsigned short* __restrict__ h_bf,
    const int* __restrict__ ei,
    const float* __restrict__ ea,
    const float* __restrict__ emask,
    const unsigned short* __restrict__ W1p,  // 288x128 packed
    const float* __restrict__ bm1,
    const unsigned short* __restrict__ W2p,  // 128x128 packed
    const float* __restrict__ bm2,
    const float* __restrict__ Wa, const float* __restrict__ ba,
    float* __restrict__ agg)
{
    __shared__ __align__(16) unsigned short s_X[64][296]; // 288 K + 8 pad
    __shared__ __align__(16) unsigned short s_H[64][136]; // 128 + 8 pad
    __shared__ int   s_row[64];
    __shared__ float s_mask[64];
    __shared__ float s_att[64];

    const int tid = threadIdx.x;
    const int e0  = blockIdx.x * 64;
    const int q   = tid & 15;          // MFMA "col/row-in-frag" lane id
    const int g   = (tid >> 4) & 3;    // MFMA k-group
    const int wn0 = (tid >> 6) * 32;   // wave's output-col base

    if (tid < 64) {
        s_row[tid]  = ei[e0 + tid];
        s_mask[tid] = emask[e0 + tid];
        s_att[tid]  = 0.f;
    }
    // gather h[row] (cols 0..127) and h[col] (cols 128..255), bf16 16B chunks
    for (int id = tid; id < 2048; id += 256) {
        int e   = (id >> 4) & 63;
        int off = id & 15;
        int node = (id < 1024) ? ei[e0 + e] : ei[E_TOT + e0 + e];
        s16x8 v = *reinterpret_cast<const s16x8*>(h_bf + (size_t)node * DIM + off * 8);
        int cb = ((id < 1024) ? 0 : DIM) + off * 8;
        *reinterpret_cast<s16x8*>(&s_X[e][cb]) = v;
    }
    // edge_attr (f32 -> bf16), cols 256..271
    if (tid < 128) {
        int e = tid >> 1, off = (tid & 1) * 8;
        const float4* s = reinterpret_cast<const float4*>(
            ea + (size_t)(e0 + e) * EDGE_DIM + off);
        float4 a = s[0], b = s[1];
        unsigned short* d = &s_X[e][2 * DIM + off];
        d[0] = f2bf(a.x); d[1] = f2bf(a.y); d[2] = f2bf(a.z); d[3] = f2bf(a.w);
        d[4] = f2bf(b.x); d[5] = f2bf(b.y); d[6] = f2bf(b.z); d[7] = f2bf(b.w);
    }
    // zero K-pad cols 272..287
    if (tid < 64) {
        s16x8 z = (s16x8)0;
        *reinterpret_cast<s16x8*>(&s_X[tid][272]) = z;
        *reinterpret_cast<s16x8*>(&s_X[tid][280]) = z;
    }

    // W1 fragments in registers: 9 k-steps x 2 n-frags
    s16x8 w1[9][2];
    #pragma unroll
    for (int s = 0; s < 9; ++s)
        #pragma unroll
        for (int nj = 0; nj < 2; ++nj)
            w1[s][nj] = *reinterpret_cast<const s16x8*>(
                W1p + (((size_t)(s * 4 + g) * DIM) + wn0 + nj * 16 + q) * 8);

    __syncthreads();

    // ---------------- layer 1 ----------------
    f32x4 acc[4][2];
    #pragma unroll
    for (int mi = 0; mi < 4; ++mi)
        #pragma unroll
        for (int nj = 0; nj < 2; ++nj)
            acc[mi][nj] = (f32x4)0.f;

    #pragma unroll
    for (int s = 0; s < 9; ++s)
        #pragma unroll
        for (int mi = 0; mi < 4; ++mi) {
            s16x8 a = *reinterpret_cast<const s16x8*>(&s_X[mi * 16 + q][s * 32 + g * 8]);
            acc[mi][0] = MFMA16(a, w1[s][0], acc[mi][0]);
            acc[mi][1] = MFMA16(a, w1[s][1], acc[mi][1]);
        }

    // bias + silu -> s_H (bf16)
    {
        float b1[2] = { bm1[wn0 + q], bm1[wn0 + 16 + q] };
        #pragma unroll
        for (int mi = 0; mi < 4; ++mi)
            #pragma unroll
            for (int nj = 0; nj < 2; ++nj)
                #pragma unroll
                for (int r = 0; r < 4; ++r)
                    s_H[mi * 16 + g * 4 + r][wn0 + nj * 16 + q] =
                        f2bf(silu_f(acc[mi][nj][r] + b1[nj]));
    }

    // W2 fragments: 4 k-steps x 2
    s16x8 w2[4][2];
    #pragma unroll
    for (int s = 0; s < 4; ++s)
        #pragma unroll
        for (int nj = 0; nj < 2; ++nj)
            w2[s][nj] = *reinterpret_cast<const s16x8*>(
                W2p + (((size_t)(s * 4 + g) * DIM) + wn0 + nj * 16 + q) * 8);

    __syncthreads();

    // ---------------- layer 2 ----------------
    #pragma unroll
    for (int mi = 0; mi < 4; ++mi)
        #pragma unroll
        for (int nj = 0; nj < 2; ++nj)
            acc[mi][nj] = (f32x4)0.f;

    #pragma unroll
    for (int s = 0; s < 4; ++s)
        #pragma unroll
        for (int mi = 0; mi < 4; ++mi) {
            s16x8 a = *reinterpret_cast<const s16x8*>(&s_H[mi * 16 + q][s * 32 + g * 8]);
            acc[mi][0] = MFMA16(a, w2[s][0], acc[mi][0]);
            acc[mi][1] = MFMA16(a, w2[s][1], acc[mi][1]);
        }

    // bias + silu; attention partial dot; reduce within 16-lane groups
    {
        float b2[2] = { bm2[wn0 + q], bm2[wn0 + 16 + q] };
        float wa[2] = { Wa[wn0 + q], Wa[wn0 + 16 + q] };
        #pragma unroll
        for (int mi = 0; mi < 4; ++mi)
            #pragma unroll
            for (int r = 0; r < 4; ++r) {
                float v0 = silu_f(acc[mi][0][r] + b2[0]);
                float v1 = silu_f(acc[mi][1][r] + b2[1]);
                acc[mi][0][r] = v0; acc[mi][1][r] = v1;
                float p = v0 * wa[0] + v1 * wa[1];
                p += __shfl_xor(p, 1, 64);
                p += __shfl_xor(p, 2, 64);
                p += __shfl_xor(p, 4, 64);
                p += __shfl_xor(p, 8, 64);
                if (q == 0) atomicAdd(&s_att[mi * 16 + g * 4 + r], p);
            }
    }
    __syncthreads();

    // scale + scatter
    {
        const float ba0 = ba[0];
        #pragma unroll
        for (int mi = 0; mi < 4; ++mi)
            #pragma unroll
            for (int r = 0; r < 4; ++r) {
                int e = mi * 16 + g * 4 + r;
                float sc = sigmoid_f(s_att[e] + ba0) * s_mask[e];
                float* dst = agg + (size_t)s_row[e] * DIM;
                atomicAdd(dst + wn0 + q,      acc[mi][0][r] * sc);
                atomicAdd(dst + wn0 + 16 + q, acc[mi][1][r] * sc);
            }
    }
}

// ---------------------------------------------------------------------------
// Node kernel: 64 nodes/block, same MFMA template, K=256 ([h | agg])
// ---------------------------------------------------------------------------
__global__ __launch_bounds__(256, 2) void node_kernel(
    const unsigned short* __restrict__ h_bf,
    const float* __restrict__ agg,
    const float* __restrict__ h,
    const float* __restrict__ flags,
    const unsigned short* __restrict__ Wn1p,  // 256x128 packed
    const float* __restrict__ bn1,
    const unsigned short* __restrict__ Wn2p,  // 128x128 packed
    const float* __restrict__ bn2,
    float* __restrict__ out)
{
    __shared__ __align__(16) unsigned short s_X[64][264]; // 256 K + 8 pad
    __shared__ __align__(16) unsigned short s_H[64][136];

    const int tid = threadIdx.x;
    const int nb0 = blockIdx.x * 64;
    const int q   = tid & 15;
    const int g   = (tid >> 4) & 3;
    const int wn0 = (tid >> 6) * 32;

    // gather h_bf (cols 0..127)
    for (int id = tid; id < 1024; id += 256) {
        int nl = id >> 4, off = id & 15;
        int n = nb0 + nl;
        s16x8 v = (s16x8)0;
        if (n < NN)
            v = *reinterpret_cast<const s16x8*>(h_bf + (size_t)n * DIM + off * 8);
        *reinterpret_cast<s16x8*>(&s_X[nl][off * 8]) = v;
    }
    // gather agg (f32 -> bf16, cols 128..255)
    for (int id = tid; id < 1024; id += 256) {
        int nl = id >> 4, off = id & 15;
        int n = nb0 + nl;
        unsigned short* d = &s_X[nl][DIM + off * 8];
        if (n < NN) {
            const float4* s = reinterpret_cast<const float4*>(agg + (size_t)n * DIM + off * 8);
            float4 a = s[0], b = s[1];
            d[0] = f2bf(a.x); d[1] = f2bf(a.y); d[2] = f2bf(a.z); d[3] = f2bf(a.w);
            d[4] = f2bf(b.x); d[5] = f2bf(b.y); d[6] = f2bf(b.z); d[7] = f2bf(b.w);
        } else {
            s16x8 z = (s16x8)0;
            *reinterpret_cast<s16x8*>(d) = z;
        }
    }

    s16x8 w1[8][2];
    #pragma unroll
    for (int s = 0; s < 8; ++s)
        #pragma unroll
        for (int nj = 0; nj < 2; ++nj)
            w1[s][nj] = *reinterpret_cast<const s16x8*>(
                Wn1p + (((size_t)(s * 4 + g) * DIM) + wn0 + nj * 16 + q) * 8);

    __syncthreads();

    f32x4 acc[4][2];
    #pragma unroll
    for (int mi = 0; mi < 4; ++mi)
        #pragma unroll
        for (int nj = 0; nj < 2; ++nj)
            acc[mi][nj] = (f32x4)0.f;

    #pragma unroll
    for (int s = 0; s < 8; ++s)
        #pragma unroll
        for (int mi = 0; mi < 4; ++mi) {
            s16x8 a = *reinterpret_cast<const s16x8*>(&s_X[mi * 16 + q][s * 32 + g * 8]);
            acc[mi][0] = MFMA16(a, w1[s][0], acc[mi][0]);
            acc[mi][1] = MFMA16(a, w1[s][1], acc[mi][1]);
        }

    {
        float b1[2] = { bn1[wn0 + q], bn1[wn0 + 16 + q] };
        #pragma unroll
        for (int mi = 0; mi < 4; ++mi)
            #pragma unroll
            for (int nj = 0; nj < 2; ++nj)
                #pragma unroll
                for (int r = 0; r < 4; ++r)
                    s_H[mi * 16 + g * 4 + r][wn0 + nj * 16 + q] =
                        f2bf(silu_f(acc[mi][nj][r] + b1[nj]));
    }

    s16x8 w2[4][2];
    #pragma unroll
    for (int s = 0; s < 4; ++s)
        #pragma unroll
        for (int nj = 0; nj < 2; ++nj)
            w2[s][nj] = *reinterpret_cast<const s16x8*>(
                Wn2p + (((size_t)(s * 4 + g) * DIM) + wn0 + nj * 16 + q) * 8);

    __syncthreads();

    #pragma unroll
    for (int mi = 0; mi < 4; ++mi)
        #pragma unroll
        for (int nj = 0; nj < 2; ++nj)
            acc[mi][nj] = (f32x4)0.f;

    #pragma unroll
    for (int s = 0; s < 4; ++s)
        #pragma unroll
        for (int mi = 0; mi < 4; ++mi) {
            s16x8 a = *reinterpret_cast<const s16x8*>(&s_H[mi * 16 + q][s * 32 + g * 8]);
            acc[mi][0] = MFMA16(a, w2[s][0], acc[mi][0]);
            acc[mi][1] = MFMA16(a, w2[s][1], acc[mi][1]);
        }

    {
        float b2[2] = { bn2[wn0 + q], bn2[wn0 + 16 + q] };
        #pragma unroll
        for (int mi = 0; mi < 4; ++mi)
            #pragma unroll
            for (int r = 0; r < 4; ++r) {
                int n = nb0 + mi * 16 + g * 4 + r;
                if (n < NN) {
                    float fl = flags[n];
                    int c0 = wn0 + q, c1 = wn0 + 16 + q;
                    size_t b = (size_t)n * DIM;
                    out[b + c0] = (h[b + c0] + acc[mi][0][r] + b2[0]) * fl;
                    out[b + c1] = (h[b + c1] + acc[mi][1][r] + b2[1]) * fl;
                }
            }
    }
}

extern "C" void kernel_launch(void* const* d_in, const int* in_sizes, int n_in,
                              void* d_out, int out_size, void* d_ws, size_t ws_size,
                              hipStream_t stream) {
    const float* h     = (const float*)d_in[0];
    const int*   ei    = (const int*)  d_in[1];
    const float* ea    = (const float*)d_in[2];
    const float* flags = (const float*)d_in[3];
    const float* emask = (const float*)d_in[4];
    const float* Wm1   = (const float*)d_in[5];
    const float* bm1   = (const float*)d_in[6];
    const float* Wm2   = (const float*)d_in[7];
    const float* bm2   = (const float*)d_in[8];
    const float* Wa    = (const float*)d_in[9];
    const float* ba    = (const float*)d_in[10];
    const float* Wn1   = (const float*)d_in[11];
    const float* bn1   = (const float*)d_in[12];
    const float* Wn2   = (const float*)d_in[13];
    const float* bn2   = (const float*)d_in[14];
    float* out = (float*)d_out;

    char* ws = (char*)d_ws;
    float*          agg  = (float*)          (ws);                 // 10,240,000 B
    unsigned short* h_bf = (unsigned short*) (ws + 10240000);      //  5,120,000 B
    unsigned short* W1p  = (unsigned short*) (ws + 15360000);      //     73,728 B
    unsigned short* W2p  = (unsigned short*) (ws + 15433728);      //     32,768 B
    unsigned short* Wn1p = (unsigned short*) (ws + 15466496);      //     65,536 B
    unsigned short* Wn2p = (unsigned short*) (ws + 15532032);      //     32,768 B

    hipMemsetAsync(agg, 0, (size_t)NN * DIM * sizeof(float), stream);
    prep_h_kernel<<<(NN * DIM / 4 + 255) / 256, 256, 0, stream>>>(h, h_bf, NN * DIM / 4);
    prep_w_kernel<<<(288 * 128 + 255) / 256, 256, 0, stream>>>(Wm1, W1p, 272, 288 * 128);
    prep_w_kernel<<<(128 * 128 + 255) / 256, 256, 0, stream>>>(Wm2, W2p, 128, 128 * 128);
    prep_w_kernel<<<(256 * 128 + 255) / 256, 256, 0, stream>>>(Wn1, Wn1p, 256, 256 * 128);
    prep_w_kernel<<<(128 * 128 + 255) / 256, 256, 0, stream>>>(Wn2, Wn2p, 128, 128 * 128);

    edge_kernel<<<E_TOT / 64, 256, 0, stream>>>(h_bf, ei, ea, emask,
                                                W1p, bm1, W2p, bm2, Wa, ba, agg);
    node_kernel<<<(NN + 63) / 64, 256, 0, stream>>>(h_bf, agg, h, flags,
                                                    Wn1p, bn1, Wn2p, bn2, out);
}

// Round 3
// 306.015 us; speedup vs baseline: 4.1860x; 1.4282x over previous
//
#include <hip/hip_runtime.h>
#include <math.h>

#define E_TOT   640000
#define NN      20000
#define DIM     128
#define EDGE_DIM 16

typedef float f32x4 __attribute__((ext_vector_type(4)));
typedef short s16x8 __attribute__((ext_vector_type(8)));
typedef __bf16 bfx8 __attribute__((ext_vector_type(8)));

__device__ __forceinline__ unsigned short f2bf(float f) {
    unsigned u = __builtin_bit_cast(unsigned, f);
    u += 0x7fffu + ((u >> 16) & 1u);
    return (unsigned short)(u >> 16);
}
__device__ __forceinline__ float silu_f(float x)    { return x / (1.0f + __expf(-x)); }
__device__ __forceinline__ float sigmoid_f(float x) { return 1.0f / (1.0f + __expf(-x)); }

#define MFMA16(a, b, c) __builtin_amdgcn_mfma_f32_16x16x32_bf16( \
    __builtin_bit_cast(bfx8, (a)), __builtin_bit_cast(bfx8, (b)), (c), 0, 0, 0)

// ---------------------------------------------------------------------------
// prep kernels
// ---------------------------------------------------------------------------
__global__ void prep_h_kernel(const float* __restrict__ h,
                              unsigned short* __restrict__ h_bf, int n4) {
    int i = blockIdx.x * blockDim.x + threadIdx.x;
    if (i < n4) {
        float4 v = reinterpret_cast<const float4*>(h)[i];
        unsigned short* d = h_bf + i * 4;
        d[0] = f2bf(v.x); d[1] = f2bf(v.y); d[2] = f2bf(v.z); d[3] = f2bf(v.w);
    }
}

// pack W[K][128] f32 -> fragment-major bf16, K padded to Kp (zeros)
__global__ void prep_w_kernel(const float* __restrict__ W,
                              unsigned short* __restrict__ Wp,
                              int K, int tot) {   // tot = Kp*128
    int id = blockIdx.x * blockDim.x + threadIdx.x;
    if (id >= tot) return;
    int t = id & 7;
    int n = (id >> 3) & 127;
    int sg = id >> 10;
    int k = sg * 8 + t;
    Wp[id] = (k < K) ? f2bf(W[(size_t)k * DIM + n]) : (unsigned short)0;
}

// ---------------------------------------------------------------------------
// counting sort of edges by row
// ---------------------------------------------------------------------------
__global__ void hist_kernel(const int* __restrict__ ei, int* __restrict__ counts) {
    int e = blockIdx.x * blockDim.x + threadIdx.x;
    if (e < E_TOT) atomicAdd(&counts[ei[e]], 1);
}

// in-place: counts -> exclusive prefix (becomes the scatter cursor)
__global__ __launch_bounds__(1024) void scan_kernel(int* __restrict__ counts) {
    __shared__ int s[1024];
    const int tid = threadIdx.x;
    const int CH = 20;                      // 1024*20 = 20480 >= NN
    int base = tid * CH;
    int loc[CH];
    int sum = 0;
    #pragma unroll
    for (int i = 0; i < CH; ++i) {
        int idx = base + i;
        loc[i] = (idx < NN) ? counts[idx] : 0;
        sum += loc[i];
    }
    s[tid] = sum;
    __syncthreads();
    for (int off = 1; off < 1024; off <<= 1) {
        int v = (tid >= off) ? s[tid - off] : 0;
        __syncthreads();
        s[tid] += v;
        __syncthreads();
    }
    int run = s[tid] - sum;                 // exclusive prefix of this chunk
    #pragma unroll
    for (int i = 0; i < CH; ++i) {
        int idx = base + i;
        if (idx < NN) counts[idx] = run;
        run += loc[i];
    }
}

__global__ void scatter_kernel(const int* __restrict__ ei, int* __restrict__ cursor,
                               int* __restrict__ eidS, unsigned short* __restrict__ rowS) {
    int e = blockIdx.x * blockDim.x + threadIdx.x;
    if (e < E_TOT) {
        int r = ei[e];
        int p = atomicAdd(&cursor[r], 1);
        eidS[p] = e;
        rowS[p] = (unsigned short)r;
    }
}

// ---------------------------------------------------------------------------
// Edge kernel: 64 edge-slots/block, 4 waves, wave w owns cols [32w,32w+32).
// SORTED: slots are row-sorted; messages accumulate in LDS, one atomic per
// (row-run x column). LDS union: s_X (gather) -> s_H (hidden) -> s_msg.
// ---------------------------------------------------------------------------
template<bool SORTED>
__global__ __launch_bounds__(256, 4) void edge_kernel(
    const unsigned short* __restrict__ h_bf,
    const int* __restrict__ ei,
    const int* __restrict__ eidS,
    const unsigned short* __restrict__ rowS,
    const float* __restrict__ ea,
    const float* __restrict__ emask,
    const unsigned short* __restrict__ W1p,  // 288x128 packed
    const float* __restrict__ bm1,
    const unsigned short* __restrict__ W2p,  // 128x128 packed
    const float* __restrict__ bm2,
    const float* __restrict__ Wa, const float* __restrict__ ba,
    float* __restrict__ agg)
{
    __shared__ __align__(16) unsigned char s_u[64 * 296 * 2];  // 37888 B union
    __shared__ int   s_eid[64];
    __shared__ int   s_row[64];
    __shared__ int   s_col[64];
    __shared__ float s_mask[64];
    __shared__ float s_att[64];

    auto s_X   = reinterpret_cast<unsigned short(*)[296]>(s_u);
    auto s_H   = reinterpret_cast<unsigned short(*)[136]>(s_u);
    auto s_msg = reinterpret_cast<float(*)[130]>(s_u);

    const int tid = threadIdx.x;
    const int e0  = blockIdx.x * 64;
    const int q   = tid & 15;
    const int g   = (tid >> 4) & 3;
    const int wn0 = (tid >> 6) * 32;

    if (tid < 64) {
        int e = SORTED ? eidS[e0 + tid] : (e0 + tid);
        s_eid[tid]  = e;
        s_row[tid]  = SORTED ? (int)rowS[e0 + tid] : ei[e];
        s_col[tid]  = ei[E_TOT + e];
        s_mask[tid] = emask[e];
        s_att[tid]  = 0.f;
    }
    __syncthreads();

    // gather h[row] (cols 0..127) and h[col] (cols 128..255)
    for (int id = tid; id < 2048; id += 256) {
        int sl  = (id >> 4) & 63;
        int off = id & 15;
        int node = (id < 1024) ? s_row[sl] : s_col[sl];
        s16x8 v = *reinterpret_cast<const s16x8*>(h_bf + (size_t)node * DIM + off * 8);
        *reinterpret_cast<s16x8*>(&s_X[sl][((id < 1024) ? 0 : DIM) + off * 8]) = v;
    }
    // edge_attr (f32 -> bf16), cols 256..271
    if (tid < 128) {
        int sl = tid >> 1, off = (tid & 1) * 8;
        const float4* s = reinterpret_cast<const float4*>(
            ea + (size_t)s_eid[sl] * EDGE_DIM + off);
        float4 a = s[0], b = s[1];
        unsigned short* d = &s_X[sl][2 * DIM + off];
        d[0] = f2bf(a.x); d[1] = f2bf(a.y); d[2] = f2bf(a.z); d[3] = f2bf(a.w);
        d[4] = f2bf(b.x); d[5] = f2bf(b.y); d[6] = f2bf(b.z); d[7] = f2bf(b.w);
    }
    // zero K-pad cols 272..287
    if (tid < 64) {
        s16x8 z = (s16x8)0;
        *reinterpret_cast<s16x8*>(&s_X[tid][272]) = z;
        *reinterpret_cast<s16x8*>(&s_X[tid][280]) = z;
    }

    // W1 fragments in registers
    s16x8 w1[9][2];
    #pragma unroll
    for (int s = 0; s < 9; ++s)
        #pragma unroll
        for (int nj = 0; nj < 2; ++nj)
            w1[s][nj] = *reinterpret_cast<const s16x8*>(
                W1p + (((size_t)(s * 4 + g) * DIM) + wn0 + nj * 16 + q) * 8);

    __syncthreads();

    // ---------------- layer 1 ----------------
    f32x4 acc[4][2];
    #pragma unroll
    for (int mi = 0; mi < 4; ++mi)
        #pragma unroll
        for (int nj = 0; nj < 2; ++nj)
            acc[mi][nj] = (f32x4)0.f;

    #pragma unroll
    for (int s = 0; s < 9; ++s)
        #pragma unroll
        for (int mi = 0; mi < 4; ++mi) {
            s16x8 a = *reinterpret_cast<const s16x8*>(&s_X[mi * 16 + q][s * 32 + g * 8]);
            acc[mi][0] = MFMA16(a, w1[s][0], acc[mi][0]);
            acc[mi][1] = MFMA16(a, w1[s][1], acc[mi][1]);
        }

    __syncthreads();   // s_X dead; union becomes s_H

    {
        float b1[2] = { bm1[wn0 + q], bm1[wn0 + 16 + q] };
        #pragma unroll
        for (int mi = 0; mi < 4; ++mi)
            #pragma unroll
            for (int nj = 0; nj < 2; ++nj)
                #pragma unroll
                for (int r = 0; r < 4; ++r)
                    s_H[mi * 16 + g * 4 + r][wn0 + nj * 16 + q] =
                        f2bf(silu_f(acc[mi][nj][r] + b1[nj]));
    }

    s16x8 w2[4][2];
    #pragma unroll
    for (int s = 0; s < 4; ++s)
        #pragma unroll
        for (int nj = 0; nj < 2; ++nj)
            w2[s][nj] = *reinterpret_cast<const s16x8*>(
                W2p + (((size_t)(s * 4 + g) * DIM) + wn0 + nj * 16 + q) * 8);

    __syncthreads();

    // ---------------- layer 2 ----------------
    #pragma unroll
    for (int mi = 0; mi < 4; ++mi)
        #pragma unroll
        for (int nj = 0; nj < 2; ++nj)
            acc[mi][nj] = (f32x4)0.f;

    #pragma unroll
    for (int s = 0; s < 4; ++s)
        #pragma unroll
        for (int mi = 0; mi < 4; ++mi) {
            s16x8 a = *reinterpret_cast<const s16x8*>(&s_H[mi * 16 + q][s * 32 + g * 8]);
            acc[mi][0] = MFMA16(a, w2[s][0], acc[mi][0]);
            acc[mi][1] = MFMA16(a, w2[s][1], acc[mi][1]);
        }

    // bias + silu; attention partial dot, reduce within 16-lane groups
    {
        float b2[2] = { bm2[wn0 + q], bm2[wn0 + 16 + q] };
        float wa[2] = { Wa[wn0 + q], Wa[wn0 + 16 + q] };
        #pragma unroll
        for (int mi = 0; mi < 4; ++mi)
            #pragma unroll
            for (int r = 0; r < 4; ++r) {
                float v0 = silu_f(acc[mi][0][r] + b2[0]);
                float v1 = silu_f(acc[mi][1][r] + b2[1]);
                acc[mi][0][r] = v0; acc[mi][1][r] = v1;
                float p = v0 * wa[0] + v1 * wa[1];
                p += __shfl_xor(p, 1, 64);
                p += __shfl_xor(p, 2, 64);
                p += __shfl_xor(p, 4, 64);
                p += __shfl_xor(p, 8, 64);
                if (q == 0) atomicAdd(&s_att[mi * 16 + g * 4 + r], p);
            }
    }
    __syncthreads();   // s_att ready; s_H dead; union becomes s_msg

    // scaled messages -> LDS (f32)
    {
        const float ba0 = ba[0];
        #pragma unroll
        for (int mi = 0; mi < 4; ++mi)
            #pragma unroll
            for (int r = 0; r < 4; ++r) {
                int e = mi * 16 + g * 4 + r;
                float sc = sigmoid_f(s_att[e] + ba0) * s_mask[e];
                s_msg[e][wn0 + q]      = acc[mi][0][r] * sc;
                s_msg[e][wn0 + 16 + q] = acc[mi][1][r] * sc;
            }
    }
    __syncthreads();

    // segmented run-reduction: thread owns (col, half); one atomic per run
    {
        const int c  = tid >> 1;
        const int hb = tid & 1;
        int   e    = hb * 32;
        float sum  = s_msg[e][c];
        int   prow = s_row[e];
        #pragma unroll 4
        for (int i = 1; i < 32; ++i) {
            int ee = hb * 32 + i;
            int r  = s_row[ee];
            float v = s_msg[ee][c];
            if (r != prow) {
                atomicAdd(agg + (size_t)prow * DIM + c, sum);
                sum = v; prow = r;
            } else {
                sum += v;
            }
        }
        atomicAdd(agg + (size_t)prow * DIM + c, sum);
    }
}

// ---------------------------------------------------------------------------
// Node kernel: [h | agg] @ Wn1 -> silu -> @Wn2 -> residual -> flags
// LDS union: s_X -> s_H
// ---------------------------------------------------------------------------
__global__ __launch_bounds__(256, 4) void node_kernel(
    const unsigned short* __restrict__ h_bf,
    const float* __restrict__ agg,
    const float* __restrict__ h,
    const float* __restrict__ flags,
    const unsigned short* __restrict__ Wn1p,  // 256x128 packed
    const float* __restrict__ bn1,
    const unsigned short* __restrict__ Wn2p,  // 128x128 packed
    const float* __restrict__ bn2,
    float* __restrict__ out)
{
    __shared__ __align__(16) unsigned char s_u[64 * 264 * 2];  // 33792 B union
    auto s_X = reinterpret_cast<unsigned short(*)[264]>(s_u);
    auto s_H = reinterpret_cast<unsigned short(*)[136]>(s_u);

    const int tid = threadIdx.x;
    const int nb0 = blockIdx.x * 64;
    const int q   = tid & 15;
    const int g   = (tid >> 4) & 3;
    const int wn0 = (tid >> 6) * 32;

    for (int id = tid; id < 1024; id += 256) {
        int nl = id >> 4, off = id & 15;
        int n = nb0 + nl;
        s16x8 v = (s16x8)0;
        if (n < NN)
            v = *reinterpret_cast<const s16x8*>(h_bf + (size_t)n * DIM + off * 8);
        *reinterpret_cast<s16x8*>(&s_X[nl][off * 8]) = v;
    }
    for (int id = tid; id < 1024; id += 256) {
        int nl = id >> 4, off = id & 15;
        int n = nb0 + nl;
        unsigned short* d = &s_X[nl][DIM + off * 8];
        if (n < NN) {
            const float4* s = reinterpret_cast<const float4*>(agg + (size_t)n * DIM + off * 8);
            float4 a = s[0], b = s[1];
            d[0] = f2bf(a.x); d[1] = f2bf(a.y); d[2] = f2bf(a.z); d[3] = f2bf(a.w);
            d[4] = f2bf(b.x); d[5] = f2bf(b.y); d[6] = f2bf(b.z); d[7] = f2bf(b.w);
        } else {
            s16x8 z = (s16x8)0;
            *reinterpret_cast<s16x8*>(d) = z;
        }
    }

    s16x8 w1[8][2];
    #pragma unroll
    for (int s = 0; s < 8; ++s)
        #pragma unroll
        for (int nj = 0; nj < 2; ++nj)
            w1[s][nj] = *reinterpret_cast<const s16x8*>(
                Wn1p + (((size_t)(s * 4 + g) * DIM) + wn0 + nj * 16 + q) * 8);

    __syncthreads();

    f32x4 acc[4][2];
    #pragma unroll
    for (int mi = 0; mi < 4; ++mi)
        #pragma unroll
        for (int nj = 0; nj < 2; ++nj)
            acc[mi][nj] = (f32x4)0.f;

    #pragma unroll
    for (int s = 0; s < 8; ++s)
        #pragma unroll
        for (int mi = 0; mi < 4; ++mi) {
            s16x8 a = *reinterpret_cast<const s16x8*>(&s_X[mi * 16 + q][s * 32 + g * 8]);
            acc[mi][0] = MFMA16(a, w1[s][0], acc[mi][0]);
            acc[mi][1] = MFMA16(a, w1[s][1], acc[mi][1]);
        }

    __syncthreads();   // s_X dead

    {
        float b1[2] = { bn1[wn0 + q], bn1[wn0 + 16 + q] };
        #pragma unroll
        for (int mi = 0; mi < 4; ++mi)
            #pragma unroll
            for (int nj = 0; nj < 2; ++nj)
                #pragma unroll
                for (int r = 0; r < 4; ++r)
                    s_H[mi * 16 + g * 4 + r][wn0 + nj * 16 + q] =
                        f2bf(silu_f(acc[mi][nj][r] + b1[nj]));
    }

    s16x8 w2[4][2];
    #pragma unroll
    for (int s = 0; s < 4; ++s)
        #pragma unroll
        for (int nj = 0; nj < 2; ++nj)
            w2[s][nj] = *reinterpret_cast<const s16x8*>(
                Wn2p + (((size_t)(s * 4 + g) * DIM) + wn0 + nj * 16 + q) * 8);

    __syncthreads();

    #pragma unroll
    for (int mi = 0; mi < 4; ++mi)
        #pragma unroll
        for (int nj = 0; nj < 2; ++nj)
            acc[mi][nj] = (f32x4)0.f;

    #pragma unroll
    for (int s = 0; s < 4; ++s)
        #pragma unroll
        for (int mi = 0; mi < 4; ++mi) {
            s16x8 a = *reinterpret_cast<const s16x8*>(&s_H[mi * 16 + q][s * 32 + g * 8]);
            acc[mi][0] = MFMA16(a, w2[s][0], acc[mi][0]);
            acc[mi][1] = MFMA16(a, w2[s][1], acc[mi][1]);
        }

    {
        float b2[2] = { bn2[wn0 + q], bn2[wn0 + 16 + q] };
        #pragma unroll
        for (int mi = 0; mi < 4; ++mi)
            #pragma unroll
            for (int r = 0; r < 4; ++r) {
                int n = nb0 + mi * 16 + g * 4 + r;
                if (n < NN) {
                    float fl = flags[n];
                    int c0 = wn0 + q, c1 = wn0 + 16 + q;
                    size_t b = (size_t)n * DIM;
                    out[b + c0] = (h[b + c0] + acc[mi][0][r] + b2[0]) * fl;
                    out[b + c1] = (h[b + c1] + acc[mi][1][r] + b2[1]) * fl;
                }
            }
    }
}

extern "C" void kernel_launch(void* const* d_in, const int* in_sizes, int n_in,
                              void* d_out, int out_size, void* d_ws, size_t ws_size,
                              hipStream_t stream) {
    const float* h     = (const float*)d_in[0];
    const int*   ei    = (const int*)  d_in[1];
    const float* ea    = (const float*)d_in[2];
    const float* flags = (const float*)d_in[3];
    const float* emask = (const float*)d_in[4];
    const float* Wm1   = (const float*)d_in[5];
    const float* bm1   = (const float*)d_in[6];
    const float* Wm2   = (const float*)d_in[7];
    const float* bm2   = (const float*)d_in[8];
    const float* Wa    = (const float*)d_in[9];
    const float* ba    = (const float*)d_in[10];
    const float* Wn1   = (const float*)d_in[11];
    const float* bn1   = (const float*)d_in[12];
    const float* Wn2   = (const float*)d_in[13];
    const float* bn2   = (const float*)d_in[14];
    float* out = (float*)d_out;

    char* ws = (char*)d_ws;
    float*          agg   = (float*)         (ws);                 // 10,240,000
    unsigned short* h_bf  = (unsigned short*)(ws + 10240000);      //  5,120,000
    unsigned short* W1p   = (unsigned short*)(ws + 15360000);      //     73,728
    unsigned short* W2p   = (unsigned short*)(ws + 15433728);      //     32,768
    unsigned short* Wn1p  = (unsigned short*)(ws + 15466496);      //     65,536
    unsigned short* Wn2p  = (unsigned short*)(ws + 15532032);      //     32,768
    int*            cnts  = (int*)           (ws + 15564800);      //     80,000
    int*            eidS  = (int*)           (ws + 15644800);      //  2,560,000
    unsigned short* rowS  = (unsigned short*)(ws + 18204800);      //  1,280,000
    const size_t WS_NEED = 19484800;

    const bool sorted = (ws_size >= WS_NEED);

    hipMemsetAsync(agg, 0, (size_t)NN * DIM * sizeof(float), stream);
    prep_h_kernel<<<(NN * DIM / 4 + 255) / 256, 256, 0, stream>>>(h, h_bf, NN * DIM / 4);
    prep_w_kernel<<<(288 * 128 + 255) / 256, 256, 0, stream>>>(Wm1, W1p, 272, 288 * 128);
    prep_w_kernel<<<(128 * 128 + 255) / 256, 256, 0, stream>>>(Wm2, W2p, 128, 128 * 128);
    prep_w_kernel<<<(256 * 128 + 255) / 256, 256, 0, stream>>>(Wn1, Wn1p, 256, 256 * 128);
    prep_w_kernel<<<(128 * 128 + 255) / 256, 256, 0, stream>>>(Wn2, Wn2p, 128, 128 * 128);

    if (sorted) {
        hipMemsetAsync(cnts, 0, NN * sizeof(int), stream);
        hist_kernel<<<(E_TOT + 255) / 256, 256, 0, stream>>>(ei, cnts);
        scan_kernel<<<1, 1024, 0, stream>>>(cnts);
        scatter_kernel<<<(E_TOT + 255) / 256, 256, 0, stream>>>(ei, cnts, eidS, rowS);
        edge_kernel<true><<<E_TOT / 64, 256, 0, stream>>>(
            h_bf, ei, eidS, rowS, ea, emask, W1p, bm1, W2p, bm2, Wa, ba, agg);
    } else {
        edge_kernel<false><<<E_TOT / 64, 256, 0, stream>>>(
            h_bf, ei, eidS, rowS, ea, emask, W1p, bm1, W2p, bm2, Wa, ba, agg);
    }

    node_kernel<<<(NN + 63) / 64, 256, 0, stream>>>(h_bf, agg, h, flags,
                                                    Wn1p, bn1, Wn2p, bn2, out);
}